// Round 4
// baseline (289.796 us; speedup 1.0000x reference)
//
#include <hip/hip_runtime.h>
#include <hip/hip_bf16.h>
#include <hip/hip_fp16.h>

typedef __attribute__((ext_vector_type(8))) _Float16 half8;
typedef __attribute__((ext_vector_type(4))) float f32x4;

#define N_B 8
#define C_DIM 256
#define S_DIM 4096

__device__ __forceinline__ _Float16 f2h(float f) { return (_Float16)f; }

__device__ __forceinline__ f32x4 mfma16(half8 a, half8 b, f32x4 c) {
  return __builtin_amdgcn_mfma_f32_16x16x32_f16(a, b, c, 0, 0, 0);
}

__device__ __forceinline__ void glds16(const _Float16* src, _Float16* dst) {
  __builtin_amdgcn_global_load_lds(
      (const __attribute__((address_space(1))) void*)src,
      (__attribute__((address_space(3))) void*)dst, 16, 0, 0);
}

// Ps swizzle: phys half index for logical (srow in [0,128), tcol in [0,64))
// chunk key ((srow>>2)&3)<<1 spreads write q-groups AND read rows across banks.
__device__ __forceinline__ int ps_idx(int srow, int tcol) {
  return srow * 64 + ((((tcol >> 3) ^ (((srow >> 2) & 3) << 1)) << 3) | (tcol & 7));
}

// ---- K0: transpose x (n,C,S) fp32 -> xT (n,S,C) fp16 ----
__global__ __launch_bounds__(256) void k_transpose(const float* __restrict__ x,
                                                   _Float16* __restrict__ xT) {
  __shared__ _Float16 tile[64][65];
  int n = blockIdx.z, cb = blockIdx.y * 64, sb = blockIdx.x * 64;
  const float* xp = x + ((size_t)n * C_DIM + cb) * S_DIM + sb;
  int t = threadIdx.x;
#pragma unroll
  for (int p = 0; p < 4; ++p) {
    int row = p * 16 + (t >> 4);
    int col = (t & 15) * 4;
    float4 v4 = *(const float4*)(xp + (size_t)row * S_DIM + col);
    tile[row][col + 0] = f2h(v4.x);
    tile[row][col + 1] = f2h(v4.y);
    tile[row][col + 2] = f2h(v4.z);
    tile[row][col + 3] = f2h(v4.w);
  }
  __syncthreads();
  _Float16* op = xT + ((size_t)n * S_DIM + sb) * C_DIM + cb;
#pragma unroll
  for (int p = 0; p < 2; ++p) {
    int srow = p * 32 + (t >> 3);
    int ccol = (t & 7) * 8;
    half8 u;
#pragma unroll
    for (int i = 0; i < 8; ++i) u[i] = tile[ccol + i][srow];
    *(half8*)(op + (size_t)srow * C_DIM + ccol) = u;
  }
}

// ---- K0b: weights fp32 -> fp16; Wq pre-scaled by log2(e) so scores are base-2 ----
__global__ __launch_bounds__(256) void k_wconv(const float* __restrict__ w0, const float* __restrict__ w1,
                                               const float* __restrict__ w2, const float* __restrict__ w3,
                                               _Float16* __restrict__ Wh) {
  int idx = blockIdx.x * 256 + threadIdx.x;
  const float* srcs[4] = {w0, w1, w2, w3};
#pragma unroll
  for (int j = 0; j < 4; ++j) {
    const float* s = srcs[j];
    float sc = (j == 0) ? 1.4426950408889634f : 1.0f;
    for (int i = idx; i < C_DIM * C_DIM; i += 16384) Wh[j * C_DIM * C_DIM + i] = f2h(s[i] * sc);
  }
}

// ---- K1: projection GEMMs ----
__global__ __launch_bounds__(256) void k_proj(const _Float16* __restrict__ xT, const _Float16* __restrict__ Wh,
                                              _Float16* __restrict__ qT, _Float16* __restrict__ kT,
                                              _Float16* __restrict__ vv, float* __restrict__ outp) {
  __shared__ __align__(16) _Float16 As[128][72];
  __shared__ __align__(16) _Float16 Bs[128][72];
  int job = blockIdx.y;
  int n = job >> 2, j = job & 3;
  const _Float16* A;
  const _Float16* B;
  int tm, tn, ldo;
  _Float16* obf = nullptr;
  float* of32 = nullptr;
  const _Float16* xTn = xT + (size_t)n * S_DIM * C_DIM;
  if (j < 2) {
    A = xTn;
    B = Wh + j * C_DIM * C_DIM;
    tm = blockIdx.x >> 1; tn = blockIdx.x & 1;
    obf = (j == 0 ? qT : kT) + (size_t)n * S_DIM * C_DIM;
    ldo = C_DIM;
  } else {
    A = Wh + j * C_DIM * C_DIM;
    B = xTn;
    tm = blockIdx.x >> 5; tn = blockIdx.x & 31;
    ldo = S_DIM;
    if (j == 2) obf = vv + (size_t)n * C_DIM * S_DIM;
    else of32 = outp + (size_t)n * C_DIM * S_DIM;
  }
  int t = threadIdx.x, w = t >> 6, lane = t & 63, r = lane & 15, q = lane >> 4;
  int wm = w >> 1, wn = w & 1;
  f32x4 acc[4][4] = {};
  for (int kc = 0; kc < 4; ++kc) {
#pragma unroll
    for (int p = 0; p < 4; ++p) {
      int row = p * 32 + (t >> 3), c8 = (t & 7) * 8;
      *(half8*)&As[row][c8] = *(const half8*)(A + (size_t)(tm * 128 + row) * C_DIM + kc * 64 + c8);
      *(half8*)&Bs[row][c8] = *(const half8*)(B + (size_t)(tn * 128 + row) * C_DIM + kc * 64 + c8);
    }
    __syncthreads();
#pragma unroll
    for (int kk = 0; kk < 2; ++kk) {
      half8 a[4], b[4];
#pragma unroll
      for (int mi = 0; mi < 4; ++mi) a[mi] = *(const half8*)&As[wm * 64 + mi * 16 + r][kk * 32 + q * 8];
#pragma unroll
      for (int ni = 0; ni < 4; ++ni) b[ni] = *(const half8*)&Bs[wn * 64 + ni * 16 + r][kk * 32 + q * 8];
#pragma unroll
      for (int mi = 0; mi < 4; ++mi)
#pragma unroll
        for (int ni = 0; ni < 4; ++ni)
          acc[mi][ni] = mfma16(a[mi], b[ni], acc[mi][ni]);
    }
    __syncthreads();
  }
#pragma unroll
  for (int mi = 0; mi < 4; ++mi)
#pragma unroll
    for (int ni = 0; ni < 4; ++ni)
#pragma unroll
      for (int jj = 0; jj < 4; ++jj) {
        int row = tm * 128 + wm * 64 + mi * 16 + q * 4 + jj;
        int col = tn * 128 + wn * 64 + ni * 16 + r;
        float val = acc[mi][ni][jj];
        if (obf) obf[(size_t)row * ldo + col] = f2h(val);
        else of32[(size_t)row * ldo + col] = val;
      }
}

// ---- K2: partial row sums (scores are base-2 now -> exp2f) ----
__global__ __launch_bounds__(512, 2) void k_rowsum(const _Float16* __restrict__ qT,
                                                   const _Float16* __restrict__ kT,
                                                   float* __restrict__ lpart) {
  __shared__ __align__(16) _Float16 Qs[2][64 * 256];
  int bid = blockIdx.x;
  int n = bid & 7, rest = bid >> 3;
  int tb = rest & 7, sq = rest >> 3;
  int t = threadIdx.x, w = t >> 6, lane = t & 63, r = lane & 15, q = lane >> 4;
  const _Float16* kp = kT + ((size_t)n * S_DIM + tb * 512 + w * 64) * C_DIM;
  const _Float16* qp = qT + ((size_t)n * S_DIM + sq * 1024) * C_DIM;
  half8 kf[4][8];
#pragma unroll
  for (int mt = 0; mt < 4; ++mt)
#pragma unroll
    for (int k = 0; k < 8; ++k)
      kf[mt][k] = *(const half8*)(kp + (size_t)(mt * 16 + r) * C_DIM + k * 32 + q * 8);
  int d0 = w * 1024 + lane * 16;
  int qswz = d0 ^ ((((w * 2) + (lane >> 5)) & 7) << 4);
  const char* qsrc0 = (const char*)qp + qswz;
#pragma unroll
  for (int i = 0; i < 4; ++i)
    glds16((const _Float16*)(qsrc0 + i * 8192), &Qs[0][i * 4096 + w * 512]);
  asm volatile("s_waitcnt vmcnt(0)" ::: "memory");
  __builtin_amdgcn_s_barrier();
  float sums[4][4] = {};
  for (int sc = 0; sc < 16; ++sc) {
    int cur = sc & 1, nxt = cur ^ 1;
    int sn = (sc + 1) & 15;
    const char* qb = qsrc0 + (size_t)sn * 32768;
#pragma unroll
    for (int i = 0; i < 4; ++i)
      glds16((const _Float16*)(qb + i * 8192), &Qs[nxt][i * 4096 + w * 512]);
    __builtin_amdgcn_s_setprio(1);
#pragma unroll
    for (int st = 0; st < 4; ++st) {
      f32x4 acc[4] = {};
#pragma unroll
      for (int k = 0; k < 8; ++k) {
        int srow = st * 16 + r;
        half8 b = *(const half8*)&Qs[cur][srow * 256 + ((k * 32 + q * 8) ^ ((srow & 7) << 3))];
#pragma unroll
        for (int mt = 0; mt < 4; ++mt) acc[mt] = mfma16(kf[mt][k], b, acc[mt]);
      }
#pragma unroll
      for (int mt = 0; mt < 4; ++mt)
#pragma unroll
        for (int jj = 0; jj < 4; ++jj) sums[mt][jj] += exp2f(acc[mt][jj]);
    }
    __builtin_amdgcn_s_setprio(0);
    asm volatile("s_waitcnt vmcnt(0) lgkmcnt(0)" ::: "memory");
    __builtin_amdgcn_s_barrier();
  }
#pragma unroll
  for (int mt = 0; mt < 4; ++mt)
#pragma unroll
    for (int jj = 0; jj < 4; ++jj) {
      float v = sums[mt][jj];
      v += __shfl_xor(v, 1);
      v += __shfl_xor(v, 2);
      v += __shfl_xor(v, 4);
      v += __shfl_xor(v, 8);
      if (r == 0)
        lpart[((size_t)sq * N_B + n) * S_DIM + tb * 512 + w * 64 + mt * 16 + q * 4 + jj] = v;
    }
}

// ---- K2b: fold 1/l into V ----
__global__ __launch_bounds__(256) void k_vscale(_Float16* __restrict__ vv, const float* __restrict__ lpart) {
  int idx = blockIdx.x * 256 + threadIdx.x;
  int t8 = idx & 511;
  int cn = idx >> 9;
  int n = cn >> 8;
  size_t voff = (size_t)cn * S_DIM + t8 * 8;
  half8 v = *(half8*)(vv + voff);
  const float* lp = lpart + (size_t)n * S_DIM + t8 * 8;
#pragma unroll
  for (int j = 0; j < 8; ++j) {
    float s = lp[j] + lp[N_B * S_DIM + j] + lp[2 * N_B * S_DIM + j] + lp[3 * N_B * S_DIM + j];
    v[j] = f2h((float)v[j] * (4096.0f / s));
  }
  *(half8*)(vv + voff) = v;
}

// ---- K3: attention, single barrier/tc, Ps double-buffered, QK split 2x4 ----
__global__ __launch_bounds__(512, 2) void k_attn(const _Float16* __restrict__ qT,
                                                 const _Float16* __restrict__ kT,
                                                 const _Float16* __restrict__ vv,
                                                 float* __restrict__ outp) {
  __shared__ __align__(16) _Float16 Kb[2][64 * 256];   // 64KB
  __shared__ __align__(16) _Float16 Vb[2][256 * 64];   // 64KB
  __shared__ __align__(16) _Float16 Ps[2][128 * 64];   // 32KB
  int bid = blockIdx.x;
  int n = bid & 7, sb = bid >> 3;
  int t = threadIdx.x, w = t >> 6, lane = t & 63, r = lane & 15, q = lane >> 4;
  int sh = w & 1, tq = w >> 1;    // QK: s-half(64) x t-quarter(16)
  int cg = w >> 1, sg = w & 1;    // PV: c-quarter(64) x s-half(64)
  const _Float16* qp = qT + ((size_t)n * S_DIM + sb * 128) * C_DIM;
  const _Float16* kpn = kT + (size_t)n * S_DIM * C_DIM;
  const _Float16* vvn = vv + (size_t)n * C_DIM * S_DIM;

  int d0 = w * 1024 + lane * 16;
  int kswz = d0 ^ ((((w * 2) + (lane >> 5)) & 7) << 4);
  const char* ksrc0 = (const char*)kpn + kswz;
  int vrow = w * 8 + (lane >> 3);
  int vcol = (((lane & 7) * 16) ^ (((lane >> 3) & 7) << 4)) >> 1;
  const _Float16* vsrc0 = vvn + (size_t)vrow * S_DIM + vcol;

  half8 qreg[4][8];
#pragma unroll
  for (int mi = 0; mi < 4; ++mi)
#pragma unroll
    for (int k = 0; k < 8; ++k)
      qreg[mi][k] = *(const half8*)(qp + (size_t)(sh * 64 + mi * 16 + r) * C_DIM + k * 32 + q * 8);

  // prologue: stage tile 0
#pragma unroll
  for (int i = 0; i < 4; ++i)
    glds16((const _Float16*)(ksrc0 + i * 8192), &Kb[0][i * 4096 + w * 512]);
#pragma unroll
  for (int i = 0; i < 4; ++i)
    glds16(vsrc0 + (size_t)i * 64 * S_DIM, &Vb[0][i * 4096 + w * 512]);
  asm volatile("s_waitcnt vmcnt(0)" ::: "memory");
  __builtin_amdgcn_s_barrier();

  f32x4 acc[4][4] = {};
  for (int tc = 0; tc < 64; ++tc) {
    int cur = tc & 1, nxt = cur ^ 1;
    int tn = (tc + 1) & 63;
    // issue K(tc+1) -> Kb[nxt]  (last readers: QK(tc-1), before BAR(tc-1))
    const char* kb = ksrc0 + (size_t)tn * 32768;
#pragma unroll
    for (int i = 0; i < 4; ++i)
      glds16((const _Float16*)(kb + i * 8192), &Kb[nxt][i * 4096 + w * 512]);
    // QK^T: scores^T (s rows, t cols), C-init -4 folds the /16
    f32x4 pacc[4];
#pragma unroll
    for (int mi = 0; mi < 4; ++mi)
#pragma unroll
      for (int jj = 0; jj < 4; ++jj) pacc[mi][jj] = -4.0f;
    __builtin_amdgcn_s_setprio(1);
#pragma unroll
    for (int k = 0; k < 8; ++k) {
      int trow = tq * 16 + r;
      half8 b = *(const half8*)&Kb[cur][trow * 256 + ((k * 32 + q * 8) ^ ((trow & 7) << 3))];
#pragma unroll
      for (int mi = 0; mi < 4; ++mi) pacc[mi] = mfma16(qreg[mi][k], b, pacc[mi]);
    }
    __builtin_amdgcn_s_setprio(0);
    // P = exp2(score*log2e - 4) -> Ps[cur]
#pragma unroll
    for (int mi = 0; mi < 4; ++mi)
#pragma unroll
      for (int jj = 0; jj < 4; ++jj) {
        int srow = sh * 64 + mi * 16 + q * 4 + jj;
        int tcol = tq * 16 + r;
        Ps[cur][ps_idx(srow, tcol)] = f2h(exp2f(pacc[mi][jj]));
      }
    // all own loads (K(tc+1) issued above, V(tc) issued last iter) + P writes done, then barrier
    asm volatile("s_waitcnt vmcnt(0) lgkmcnt(0)" ::: "memory");
    __builtin_amdgcn_s_barrier();
    // PV: O += V' * P
    __builtin_amdgcn_s_setprio(1);
#pragma unroll
    for (int kk = 0; kk < 2; ++kk) {
      half8 a[4];
#pragma unroll
      for (int mi = 0; mi < 4; ++mi) {
        int crow = cg * 64 + mi * 16 + r;
        a[mi] = *(const half8*)&Vb[cur][crow * 64 + ((kk * 32 + q * 8) ^ ((crow & 7) << 3))];
      }
#pragma unroll
      for (int ni = 0; ni < 4; ++ni) {
        int srow = sg * 64 + ni * 16 + r;
        half8 pb = *(const half8*)&Ps[cur][ps_idx(srow, (kk * 4 + q) << 3)];
#pragma unroll
        for (int mi = 0; mi < 4; ++mi)
          acc[mi][ni] = mfma16(a[mi], pb, acc[mi][ni]);
      }
    }
    __builtin_amdgcn_s_setprio(0);
    // issue V(tc+1) -> Vb[nxt]  (last readers: PV(tc-1), before BAR(tc))
    const _Float16* vb = vsrc0 + tn * 64;
#pragma unroll
    for (int i = 0; i < 4; ++i)
      glds16(vb + (size_t)i * 64 * S_DIM, &Vb[nxt][i * 4096 + w * 512]);
  }
  float* ob = outp + (size_t)n * C_DIM * S_DIM + (size_t)sb * 128;
#pragma unroll
  for (int mi = 0; mi < 4; ++mi)
#pragma unroll
    for (int ni = 0; ni < 4; ++ni)
#pragma unroll
      for (int jj = 0; jj < 4; ++jj) {
        int c = cg * 64 + mi * 16 + q * 4 + jj;
        int s = sg * 64 + ni * 16 + r;
        ob[(size_t)c * S_DIM + s] += acc[mi][ni][jj] * 0.00390625f;
      }
}

extern "C" void kernel_launch(void* const* d_in, const int* in_sizes, int n_in,
                              void* d_out, int out_size, void* d_ws, size_t ws_size,
                              hipStream_t stream) {
  const float* x  = (const float*)d_in[0];
  const float* Wq = (const float*)d_in[1];
  const float* Wk = (const float*)d_in[2];
  const float* Wv = (const float*)d_in[3];
  const float* Wl = (const float*)d_in[4];
  float* out = (float*)d_out;
  char* base = (char*)d_ws;
  const size_t MB = 1024 * 1024;
  _Float16* xT = (_Float16*)(base);
  _Float16* qT = (_Float16*)(base + 16 * MB);
  _Float16* kT = (_Float16*)(base + 32 * MB);
  _Float16* vv = (_Float16*)(base + 48 * MB);
  _Float16* Wh = (_Float16*)(base + 64 * MB);
  float* lpart = (float*)(base + 64 * MB + 524288);

  k_transpose<<<dim3(64, 4, N_B), dim3(256), 0, stream>>>(x, xT);
  k_wconv<<<dim3(64), dim3(256), 0, stream>>>(Wq, Wk, Wv, Wl, Wh);
  k_proj<<<dim3(64, 32), dim3(256), 0, stream>>>(xT, Wh, qT, kT, vv, out);
  k_rowsum<<<dim3(256), dim3(512), 0, stream>>>(qT, kT, lpart);
  k_vscale<<<dim3(4096), dim3(256), 0, stream>>>(vv, lpart);
  k_attn<<<dim3(256), dim3(512), 0, stream>>>(qT, kT, vv, out);
}